// Round 8
// baseline (145.366 us; speedup 1.0000x reference)
//
#include <hip/hip_runtime.h>

typedef short bf16x8 __attribute__((ext_vector_type(8)));
typedef short bf16x4 __attribute__((ext_vector_type(4)));
typedef float f32x4 __attribute__((ext_vector_type(4)));
typedef float f32x16 __attribute__((ext_vector_type(16)));
typedef unsigned short u16;
typedef unsigned int u32;
typedef u16 u16x8 __attribute__((ext_vector_type(8)));
typedef u16 u16x4 __attribute__((ext_vector_type(4)));

#define DEV __device__ __forceinline__

DEV u16 f2bf(float f) {
  unsigned u = __float_as_uint(f);
  u += 0x7fff + ((u >> 16) & 1);  // RNE (no NaN in this workload)
  return (u16)(u >> 16);
}

DEV int pkbf(float lo, float hi) {
  return __builtin_amdgcn_perm(__float_as_uint(hi) + 0x8000u,
                               __float_as_uint(lo) + 0x8000u, 0x07060302u);
}

#define MFMA16(a, b, c) __builtin_amdgcn_mfma_f32_16x16x32_bf16(a, b, c, 0, 0, 0)
#define MFMA3216(a, b, c) __builtin_amdgcn_mfma_f32_32x32x16_bf16(a, b, c, 0, 0, 0)

#if __has_builtin(__builtin_amdgcn_mfma_f32_32x32x8bf16_1k)
#define HAVE_PV8 1
#define PVMFMA(a, b, c) __builtin_amdgcn_mfma_f32_32x32x8bf16_1k(a, b, c, 0, 0, 0)
#else
#define HAVE_PV8 0
#endif

#if __has_builtin(__builtin_amdgcn_exp2f)
#define QSCALE 0.18033688011112042f  // 0.125 * log2(e)
#define EXPFN(x) __builtin_amdgcn_exp2f(x)
#else
#define QSCALE 0.125f
#define EXPFN(x) __expf(x)
#endif

// global -> LDS direct DMA, 16B/lane; LDS dest = wave-uniform base + lane*16
#define GLD16(gp, lp)                                                     \
  __builtin_amdgcn_global_load_lds(                                       \
      (const __attribute__((address_space(1))) u32*)(gp),                 \
      (__attribute__((address_space(3))) u32*)(lp), 16, 0, 0)

#define WAIT_VM0 __builtin_amdgcn_s_waitcnt(0x0F70)    // vmcnt(0) only
#define WAIT_LGKM0 __builtin_amdgcn_s_waitcnt(0xC07F)  // lgkmcnt(0) only

// ---------------------------------------------------------------------------
// wprep: [0,1024) weight transpose+convert; [1024,3072) x1/x2 fp32->bf16.
// ---------------------------------------------------------------------------
__global__ __launch_bounds__(256) void wprep(
    const float* __restrict__ Wqk, const float* __restrict__ Wv,
    const float* __restrict__ Wout, const float* __restrict__ x1,
    const float* __restrict__ x2,
    u16* __restrict__ WqkT, u16* __restrict__ WvT, u16* __restrict__ WoutT,
    u16* __restrict__ x1b, u16* __restrict__ x2b) {
  int bx = blockIdx.x, t = threadIdx.x;
  if (bx >= 1024) {
    int bx2 = bx - 1024;
    const float* src = (bx2 < 1024) ? x1 : x2;
    u16* dst = (bx2 < 1024) ? x1b : x2b;
    long base = (long)(bx2 & 1023) * 2048 + t * 8;
    float4 a = *(const float4*)(src + base);
    float4 b = *(const float4*)(src + base + 4);
    u16x8 o;
    o[0] = f2bf(a.x); o[1] = f2bf(a.y); o[2] = f2bf(a.z); o[3] = f2bf(a.w);
    o[4] = f2bf(b.x); o[5] = f2bf(b.y); o[6] = f2bf(b.z); o[7] = f2bf(b.w);
    *(u16x8*)(dst + base) = o;
    return;
  }
  __shared__ float tf[32][33];
  const float* src; u16* dst; int Ncols; int id;
  if (bx < 512)      { id = bx;       src = Wqk;  dst = WqkT;  Ncols = 1024; }
  else if (bx < 768) { id = bx - 512; src = Wv;   dst = WvT;   Ncols = 512; }
  else               { id = bx - 768; src = Wout; dst = WoutT; Ncols = 512; }
  int tilesPerRow = Ncols >> 5;
  int tr = id / tilesPerRow, tc = id % tilesPerRow;
  int r0 = tr * 32, c0 = tc * 32;
  {
    int r = t >> 3, c4 = (t & 7) * 4;
    float4 v = *(const float4*)(src + (long)(r0 + r) * Ncols + c0 + c4);
    tf[r][c4] = v.x; tf[r][c4 + 1] = v.y; tf[r][c4 + 2] = v.z; tf[r][c4 + 3] = v.w;
  }
  __syncthreads();
  {
    int c = t >> 3, r4 = (t & 7) * 4;
    u16x4 o;
    o[0] = f2bf(tf[r4][c]); o[1] = f2bf(tf[r4 + 1][c]);
    o[2] = f2bf(tf[r4 + 2][c]); o[3] = f2bf(tf[r4 + 3][c]);
    *(u16x4*)(dst + (long)(c0 + c) * 512 + r0 + r4) = o;
  }
}

// ---------------------------------------------------------------------------
// Fused QKV GEMM v2: all-bf16 inputs, global_load_lds DMA staging (zero
// staging VGPRs/VALU), [chunk][row] LDS layout (conflict-free b128 reads),
// double-buffered, one barrier/kt. 768 blocks x 256 thr (3 blocks/CU).
// blocks [0,256): Q = x2b*WvT*QSCALE ; [256,768): K,Vt = x1b*WqkT.
// ---------------------------------------------------------------------------
__global__ __launch_bounds__(256) void qkv_gemm(
    const u16* __restrict__ x1b, const u16* __restrict__ x2b,
    const u16* __restrict__ WqkT, const u16* __restrict__ WvT,
    u16* __restrict__ out_q, u16* __restrict__ out_k, u16* __restrict__ out_vt) {
  __shared__ u16 sA[2][4096];  // A tile 128 rows x 32 k, chunk-major [c][row]
  __shared__ u16 sB[2][2048];  // B tile 64 rows x 32 k
  int bx = blockIdx.x, t = threadIdx.x;
  bool isQ = bx < 256;
  int bx2 = isQ ? bx : bx - 256;
  const u16* A = isQ ? x2b : x1b;
  const u16* BT = isQ ? WvT : WqkT;
  int m0 = (bx2 & 31) * 128, n0 = (bx2 >> 5) * 64;
  int w = t >> 6, lane = t & 63, lm = lane & 15, lq = lane >> 4;

  f32x4 zero = {0.f, 0.f, 0.f, 0.f};
  f32x4 acc[2][4];
#pragma unroll
  for (int i = 0; i < 2; ++i)
#pragma unroll
    for (int j = 0; j < 4; ++j) acc[i][j] = zero;

  // DMA source pointers: A chunk idx gidx=(w*2+j)*64+lane -> c=gidx>>7, row=gidx&127
  int gA0 = w * 128 + lane, gA1 = gA0 + 64;
  const u16* srcA0 = A + (long)(m0 + (gA0 & 127)) * 512 + (gA0 >> 7) * 8;
  const u16* srcA1 = A + (long)(m0 + (gA1 & 127)) * 512 + (gA1 >> 7) * 8;
  int gB = w * 64 + lane;  // c=gidx>>6, row=gidx&63
  const u16* srcB = BT + (long)(n0 + (gB & 63)) * 512 + (gB >> 6) * 8;
  int ldsA0 = w * 128 * 8, ldsA1 = ldsA0 + 64 * 8, ldsB = w * 64 * 8;

  auto stage = [&](int kt, int buf) {
    GLD16(srcA0 + kt * 32, &sA[buf][ldsA0]);
    GLD16(srcA1 + kt * 32, &sA[buf][ldsA1]);
    GLD16(srcB + kt * 32, &sB[buf][ldsB]);
  };

  stage(0, 0);
  __syncthreads();

  for (int kt = 0; kt < 16; ++kt) {
    int cur = kt & 1;
    if (kt < 15) stage(kt + 1, cur ^ 1);  // DMA overlaps compute below
    bf16x8 af[2], bfr[4];
    af[0] = *(const bf16x8*)(&sA[cur][(lq * 128 + w * 32 + lm) * 8]);
    af[1] = *(const bf16x8*)(&sA[cur][(lq * 128 + w * 32 + 16 + lm) * 8]);
#pragma unroll
    for (int s = 0; s < 4; ++s)
      bfr[s] = *(const bf16x8*)(&sB[cur][(lq * 64 + s * 16 + lm) * 8]);
#pragma unroll
    for (int ms = 0; ms < 2; ++ms)
#pragma unroll
      for (int s = 0; s < 4; ++s)
        acc[ms][s] = MFMA16(af[ms], bfr[s], acc[ms][s]);
    __syncthreads();  // drains vmcnt -> next buffer ready; guards reuse
  }

#pragma unroll
  for (int ms = 0; ms < 2; ++ms) {
    int gmBase = m0 + w * 32 + ms * 16 + lq * 4;
#pragma unroll
    for (int s = 0; s < 4; ++s) {
      int gc = n0 + s * 16 + lm;
      int b = gmBase >> 11, n = gmBase & 2047;
      if (isQ) {
#pragma unroll
        for (int r = 0; r < 4; ++r)
          out_q[(((long)(b << 3) + (gc >> 6)) * 2048 + n + r) * 64 + (gc & 63)] =
              f2bf(acc[ms][s][r] * QSCALE);
      } else if (gc < 512) {
#pragma unroll
        for (int r = 0; r < 4; ++r)
          out_k[(((long)(b << 3) + (gc >> 6)) * 2048 + n + r) * 64 + (gc & 63)] =
              f2bf(acc[ms][s][r]);
      } else {
        int c = gc - 512, h = c >> 6, d = c & 63;
        u16x4 vv;
#pragma unroll
        for (int r = 0; r < 4; ++r) vv[r] = f2bf(acc[ms][s][r]);
        *(u16x4*)(out_vt + (((long)(b << 3) + h) * 64 + d) * 2048 + n) = vv;
      }
    }
  }
}

// ---------------------------------------------------------------------------
// Attention v4 (byte-identical structure to R7 — frozen for attribution).
// ---------------------------------------------------------------------------
__global__ __launch_bounds__(256, 4) void attn(
    const u16* __restrict__ Q, const u16* __restrict__ K,
    const u16* __restrict__ Vt, u16* __restrict__ O) {
  int id = blockIdx.x;
  int bh = id & 15, qt = id >> 4;
  int b = bh >> 3, h = bh & 7;
  const u16* Kh = K + (long)bh * 2048 * 64;
  const u16* Vh = Vt + (long)bh * 64 * 2048;
  int t = threadIdx.x, w = t >> 6, lane = t & 63, ln = lane & 31, hi = lane >> 5;

  __shared__ u16 smem[4][2][2048];
  u16* ktile = smem[w][0];
  u16* vtile = smem[w][1];

  bf16x8 qf[4];
  {
    const u16* qp = Q + (long)bh * 2048 * 64 + (long)(qt * 32 + ln) * 64 + hi * 8;
#pragma unroll
    for (int dc = 0; dc < 4; ++dc) qf[dc] = *(const bf16x8*)(qp + dc * 16);
  }

  f32x16 accO[2];
#pragma unroll
  for (int dt = 0; dt < 2; ++dt)
#pragma unroll
    for (int i = 0; i < 16; ++i) accO[dt][i] = 0.f;
  float dacc = 0.f;

  int l8 = lane & 7, lr8 = lane >> 3;
  int l4 = lane & 3, lr16 = lane >> 2;
  const u16* gK0 = Kh + (long)(w * 512 + lr8) * 64 + (l8 ^ lr8) * 8;
  const u16* gV0 = Vh + (long)lr16 * 2048 + w * 512 + (l4 ^ (lr16 & 3)) * 8;

  auto stage = [&](int jt) {
    const u16* gk = gK0 + (long)jt * 2048;
    const u16* gv = gV0 + jt * 32;
#pragma unroll
    for (int i = 0; i < 4; ++i) {
      GLD16(gk + i * 512, ktile + i * 512);
      GLD16(gv + (long)i * 32768, vtile + i * 512);
    }
  };

  stage(0);
  WAIT_VM0;

  int s7 = ln & 7, s3 = ln & 3;
  for (int jt = 0; jt < 16; ++jt) {
    f32x16 st1, st2;
#pragma unroll
    for (int i = 0; i < 16; ++i) { st1[i] = 0.f; st2[i] = 0.f; }
    bf16x8 kf0 = *(const bf16x8*)(ktile + ln * 64 + ((0 * 2 + hi) ^ s7) * 8);
    bf16x8 kf1 = *(const bf16x8*)(ktile + ln * 64 + ((1 * 2 + hi) ^ s7) * 8);
    bf16x8 kf2 = *(const bf16x8*)(ktile + ln * 64 + ((2 * 2 + hi) ^ s7) * 8);
    bf16x8 kf3 = *(const bf16x8*)(ktile + ln * 64 + ((3 * 2 + hi) ^ s7) * 8);
    st1 = MFMA3216(kf0, qf[0], st1);
    st2 = MFMA3216(kf1, qf[1], st2);
    st1 = MFMA3216(kf2, qf[2], st1);
    st2 = MFMA3216(kf3, qf[3], st2);

    float p[16];
#pragma unroll
    for (int i = 0; i < 16; ++i) {
      float e = EXPFN(st1[i] + st2[i]);
      p[i] = e;
      dacc += e;
    }

#if HAVE_PV8
#pragma unroll
    for (int c = 0; c < 4; ++c) {
      union { int2 i2; bf16x4 v; } u;
      u.i2.x = pkbf(p[c * 4 + 0], p[c * 4 + 1]);
      u.i2.y = pkbf(p[c * 4 + 2], p[c * 4 + 3]);
#pragma unroll
      for (int dt = 0; dt < 2; ++dt) {
        bf16x4 vf = *(const bf16x4*)(vtile + (dt * 32 + ln) * 32 +
                                     ((c ^ s3) * 8) + hi * 4);
        accO[dt] = PVMFMA(vf, u.v, accO[dt]);
      }
    }
#else
#pragma unroll
    for (int c2 = 0; c2 < 2; ++c2) {
      int o0x = pkbf(p[c2 * 8 + 0], p[c2 * 8 + 1]);
      int o0y = pkbf(p[c2 * 8 + 2], p[c2 * 8 + 3]);
      int o1x = pkbf(p[c2 * 8 + 4], p[c2 * 8 + 5]);
      int o1y = pkbf(p[c2 * 8 + 6], p[c2 * 8 + 7]);
      int s0x = __shfl_xor(o0x, 32), s0y = __shfl_xor(o0y, 32);
      int s1x = __shfl_xor(o1x, 32), s1y = __shfl_xor(o1y, 32);
      union { int4 i4; bf16x8 v; } u;
      if (hi) { u.i4.x = s1x; u.i4.y = s1y; u.i4.z = o1x; u.i4.w = o1y; }
      else    { u.i4.x = o0x; u.i4.y = o0y; u.i4.z = s0x; u.i4.w = s0y; }
#pragma unroll
      for (int dt = 0; dt < 2; ++dt) {
        bf16x8 vf = *(const bf16x8*)(vtile + (dt * 32 + ln) * 32 +
                                     (((c2 * 2 + hi) ^ s3) * 8));
        accO[dt] = MFMA3216(vf, u.v, accO[dt]);
      }
    }
#endif

    if (jt < 15) {
      WAIT_LGKM0;
      stage(jt + 1);
      WAIT_VM0;
    }
  }

  __syncthreads();
  float* cb = (float*)&smem[0][0][0];
  if (w != 0) {
    float* sc = cb + (w - 1) * 2112;
#pragma unroll
    for (int dt = 0; dt < 2; ++dt)
#pragma unroll
      for (int i = 0; i < 16; ++i)
        sc[(dt * 16 + i) * 64 + hi * 32 + ln] = accO[dt][i];
    sc[2048 + hi * 32 + ln] = dacc;
  }
  __syncthreads();
  if (w == 0) {
#pragma unroll
    for (int j = 0; j < 3; ++j) {
      float* sc = cb + j * 2112;
#pragma unroll
      for (int dt = 0; dt < 2; ++dt)
#pragma unroll
        for (int i = 0; i < 16; ++i)
          accO[dt][i] += sc[(dt * 16 + i) * 64 + hi * 32 + ln];
      dacc += sc[2048 + hi * 32 + ln];
    }
    dacc += __shfl_xor(dacc, 32);
    float inv = 1.f / dacc;

    u16* Ob = O + ((long)b * 2048 + qt * 32 + ln) * 512 + h * 64;
#pragma unroll
    for (int dt = 0; dt < 2; ++dt)
#pragma unroll
      for (int gq = 0; gq < 4; ++gq) {
        u16x4 o;
#pragma unroll
        for (int rr = 0; rr < 4; ++rr) o[rr] = f2bf(accO[dt][gq * 4 + rr] * inv);
        *(u16x4*)(Ob + dt * 32 + gq * 8 + hi * 4) = o;
      }
  }
}

// ---------------------------------------------------------------------------
// out GEMM v2: DMA staging, [chunk][row] LDS, dbuf. 1024 blocks x 128 thr.
// ---------------------------------------------------------------------------
__global__ __launch_bounds__(128) void out_gemm(
    const u16* __restrict__ A, const u16* __restrict__ BT,
    float* __restrict__ out_f, const float* __restrict__ bias) {
  __shared__ u16 sA[2][2048];  // 64 rows x 32 k, [c][row]
  __shared__ u16 sB[2][1024];  // 32 rows x 32 k
  int t = threadIdx.x, bx = blockIdx.x;
  int m0 = (bx & 63) * 64, n0 = (bx >> 6) * 32;
  int w = t >> 6, lane = t & 63, lm = lane & 15, lq = lane >> 4;

  f32x4 zero = {0.f, 0.f, 0.f, 0.f};
  f32x4 acc[2][2];
#pragma unroll
  for (int i = 0; i < 2; ++i)
#pragma unroll
    for (int j = 0; j < 2; ++j) acc[i][j] = zero;

  int gA0 = w * 128 + lane, gA1 = gA0 + 64;  // c=g>>6, row=g&63
  const u16* srcA0 = A + (long)(m0 + (gA0 & 63)) * 512 + (gA0 >> 6) * 8;
  const u16* srcA1 = A + (long)(m0 + (gA1 & 63)) * 512 + (gA1 >> 6) * 8;
  int gB = w * 64 + lane;  // c=g>>5, row=g&31
  const u16* srcB = BT + (long)(n0 + (gB & 31)) * 512 + (gB >> 5) * 8;
  int ldsA0 = w * 128 * 8, ldsA1 = ldsA0 + 64 * 8, ldsB = w * 64 * 8;

  auto stage = [&](int kt, int buf) {
    GLD16(srcA0 + kt * 32, &sA[buf][ldsA0]);
    GLD16(srcA1 + kt * 32, &sA[buf][ldsA1]);
    GLD16(srcB + kt * 32, &sB[buf][ldsB]);
  };

  stage(0, 0);
  __syncthreads();

  for (int kt = 0; kt < 16; ++kt) {
    int cur = kt & 1;
    if (kt < 15) stage(kt + 1, cur ^ 1);
    bf16x8 af[2], bfr[2];
    af[0] = *(const bf16x8*)(&sA[cur][(lq * 64 + w * 32 + lm) * 8]);
    af[1] = *(const bf16x8*)(&sA[cur][(lq * 64 + w * 32 + 16 + lm) * 8]);
    bfr[0] = *(const bf16x8*)(&sB[cur][(lq * 32 + lm) * 8]);
    bfr[1] = *(const bf16x8*)(&sB[cur][(lq * 32 + 16 + lm) * 8]);
#pragma unroll
    for (int ms = 0; ms < 2; ++ms)
#pragma unroll
      for (int s = 0; s < 2; ++s)
        acc[ms][s] = MFMA16(af[ms], bfr[s], acc[ms][s]);
    __syncthreads();
  }

#pragma unroll
  for (int ms = 0; ms < 2; ++ms) {
    int gmBase = m0 + w * 32 + ms * 16 + lq * 4;
#pragma unroll
    for (int s = 0; s < 2; ++s) {
      int gc = n0 + s * 16 + lm;
      float bv = bias[gc];
#pragma unroll
      for (int r = 0; r < 4; ++r)
        out_f[(long)(gmBase + r) * 512 + gc] = acc[ms][s][r] + bv;
    }
  }
}

// ---------------------------------------------------------------------------
extern "C" void kernel_launch(void* const* d_in, const int* in_sizes, int n_in,
                              void* d_out, int out_size, void* d_ws, size_t ws_size,
                              hipStream_t stream) {
  const float* x1 = (const float*)d_in[0];
  const float* x2 = (const float*)d_in[1];
  const float* Wqk = (const float*)d_in[2];
  const float* Wv = (const float*)d_in[3];
  const float* Wout = (const float*)d_in[4];
  const float* bout = (const float*)d_in[5];
  float* out = (float*)d_out;

  u16* ws = (u16*)d_ws;
  const long SZ = 2097152;  // 2*8*2048*64
  u16* Qw = ws;
  u16* Kw = ws + SZ;
  u16* Vtw = ws + 2 * SZ;
  u16* Ow = ws + 3 * SZ;
  u16* x1b = ws + 4 * SZ;
  u16* x2b = ws + 5 * SZ;
  u16* WqkT = ws + 6 * SZ;
  u16* WvT = WqkT + 524288;
  u16* WoutT = WvT + 262144;

  wprep<<<3072, 256, 0, stream>>>(Wqk, Wv, Wout, x1, x2, WqkT, WvT, WoutT, x1b, x2b);
  qkv_gemm<<<768, 256, 0, stream>>>(x1b, x2b, WqkT, WvT, Qw, Kw, Vtw);
  attn<<<1024, 256, 0, stream>>>(Qw, Kw, Vtw, Ow);
  out_gemm<<<1024, 128, 0, stream>>>(Ow, WoutT, out, bout);
}

// Round 9
// 128.838 us; speedup vs baseline: 1.1283x; 1.1283x over previous
//
#include <hip/hip_runtime.h>

typedef short bf16x8 __attribute__((ext_vector_type(8)));
typedef short bf16x4 __attribute__((ext_vector_type(4)));
typedef float f32x4 __attribute__((ext_vector_type(4)));
typedef float f32x16 __attribute__((ext_vector_type(16)));
typedef unsigned short u16;
typedef unsigned int u32;
typedef u16 u16x8 __attribute__((ext_vector_type(8)));
typedef u16 u16x4 __attribute__((ext_vector_type(4)));

#define DEV __device__ __forceinline__

DEV u16 f2bf(float f) {
  unsigned u = __float_as_uint(f);
  u += 0x7fff + ((u >> 16) & 1);  // RNE (no NaN in this workload)
  return (u16)(u >> 16);
}

// pack 2 fp32 -> 2 bf16 in one v_perm_b32 (round-half-up; fine for P values)
DEV int pkbf(float lo, float hi) {
  return __builtin_amdgcn_perm(__float_as_uint(hi) + 0x8000u,
                               __float_as_uint(lo) + 0x8000u, 0x07060302u);
}

#define MFMA16(a, b, c) __builtin_amdgcn_mfma_f32_16x16x32_bf16(a, b, c, 0, 0, 0)
#define MFMA3216(a, b, c) __builtin_amdgcn_mfma_f32_32x32x16_bf16(a, b, c, 0, 0, 0)

#if __has_builtin(__builtin_amdgcn_mfma_f32_32x32x8bf16_1k)
#define HAVE_PV8 1
#define PVMFMA(a, b, c) __builtin_amdgcn_mfma_f32_32x32x8bf16_1k(a, b, c, 0, 0, 0)
#else
#define HAVE_PV8 0
#endif

// exp base: fold log2(e) into the Q scale when raw v_exp_f32 is reachable
#if __has_builtin(__builtin_amdgcn_exp2f)
#define QSCALE 0.18033688011112042f  // 0.125 * log2(e)
#define EXPFN(x) __builtin_amdgcn_exp2f(x)
#else
#define QSCALE 0.125f
#define EXPFN(x) __expf(x)
#endif

// global -> LDS direct DMA, 16B per lane; LDS dest = uniform base + lane*16
#define GLD16(gp, lp)                                                     \
  __builtin_amdgcn_global_load_lds(                                       \
      (const __attribute__((address_space(1))) u32*)(gp),                 \
      (__attribute__((address_space(3))) u32*)(lp), 16, 0, 0)

// ---------------------------------------------------------------------------
// wprep: transpose+convert weights to bf16 [n][k].
// ---------------------------------------------------------------------------
__global__ __launch_bounds__(256) void wprep(
    const float* __restrict__ Wqk, const float* __restrict__ Wv,
    const float* __restrict__ Wout,
    u16* __restrict__ WqkT, u16* __restrict__ WvT, u16* __restrict__ WoutT) {
  __shared__ float tf[32][33];
  int bx = blockIdx.x, t = threadIdx.x;
  const float* src; u16* dst; int Ncols; int id;
  if (bx < 512)      { id = bx;       src = Wqk;  dst = WqkT;  Ncols = 1024; }
  else if (bx < 768) { id = bx - 512; src = Wv;   dst = WvT;   Ncols = 512; }
  else               { id = bx - 768; src = Wout; dst = WoutT; Ncols = 512; }
  int tilesPerRow = Ncols >> 5;
  int tr = id / tilesPerRow, tc = id % tilesPerRow;
  int r0 = tr * 32, c0 = tc * 32;
  {
    int r = t >> 3, c4 = (t & 7) * 4;
    float4 v = *(const float4*)(src + (long)(r0 + r) * Ncols + c0 + c4);
    tf[r][c4] = v.x; tf[r][c4 + 1] = v.y; tf[r][c4 + 2] = v.z; tf[r][c4 + 3] = v.w;
  }
  __syncthreads();
  {
    int c = t >> 3, r4 = (t & 7) * 4;
    u16x4 o;
    o[0] = f2bf(tf[r4][c]); o[1] = f2bf(tf[r4 + 1][c]);
    o[2] = f2bf(tf[r4 + 2][c]); o[3] = f2bf(tf[r4 + 3][c]);
    *(u16x4*)(dst + (long)(c0 + c) * 512 + r0 + r4) = o;
  }
}

// ---------------------------------------------------------------------------
// Fused QKV GEMM: blocks [0,256) Q = x2*WvT*QSCALE ; [256,768) K,Vt = x1*WqkT.
// Block 128x64, BK=32, 4 waves, dbuf + register prefetch, fp32 A converted
// during staging (overlaps MFMA at 3 blocks/CU).
// ---------------------------------------------------------------------------
__global__ __launch_bounds__(256) void qkv_gemm(
    const float* __restrict__ x1, const float* __restrict__ x2,
    const u16* __restrict__ WqkT, const u16* __restrict__ WvT,
    u16* __restrict__ out_q, u16* __restrict__ out_k, u16* __restrict__ out_vt) {
  __shared__ u16 sA[2][128 * 40];
  __shared__ u16 sB[2][64 * 40];
  int bx = blockIdx.x, t = threadIdx.x;
  bool isQ = bx < 256;
  int bx2 = isQ ? bx : bx - 256;
  const float* Ap = isQ ? x2 : x1;
  const u16* BT = isQ ? WvT : WqkT;
  int m0 = (bx2 & 31) * 128, n0 = (bx2 >> 5) * 64;
  int w = t >> 6, l = t & 63, lm = l & 15, lq = l >> 4;

  f32x4 zero = {0.f, 0.f, 0.f, 0.f};
  f32x4 acc[2][4];
#pragma unroll
  for (int i = 0; i < 2; ++i)
#pragma unroll
    for (int j = 0; j < 4; ++j) acc[i][j] = zero;

  int sm = t >> 2;
  int skc = (t & 3) * 8;
  const float* gAf = Ap + (long)(m0 + sm) * 512 + skc;
  const u16* gB = BT + (long)(n0 + sm) * 512 + skc;

  auto loadA = [&](int kt, int rows) {
    long off = (long)rows * 512 + kt * 32;
    float4 f0 = *(const float4*)(gAf + off);
    float4 f1 = *(const float4*)(gAf + off + 4);
    bf16x8 o;
    o[0] = (short)f2bf(f0.x); o[1] = (short)f2bf(f0.y);
    o[2] = (short)f2bf(f0.z); o[3] = (short)f2bf(f0.w);
    o[4] = (short)f2bf(f1.x); o[5] = (short)f2bf(f1.y);
    o[6] = (short)f2bf(f1.z); o[7] = (short)f2bf(f1.w);
    return o;
  };

  bf16x8 a0 = loadA(0, 0);
  bf16x8 a1 = loadA(0, 64);
  bf16x8 b0 = *(const bf16x8*)(gB);
  *(bf16x8*)(sA[0] + sm * 40 + skc) = a0;
  *(bf16x8*)(sA[0] + (sm + 64) * 40 + skc) = a1;
  *(bf16x8*)(sB[0] + sm * 40 + skc) = b0;
  __syncthreads();

  for (int kt = 0; kt < 16; ++kt) {
    int cur = kt & 1;
    if (kt < 15) {
      a0 = loadA(kt + 1, 0);
      a1 = loadA(kt + 1, 64);
      b0 = *(const bf16x8*)(gB + (kt + 1) * 32);
    }
    bf16x8 af[2], bfr[4];
    af[0] = *(const bf16x8*)(sA[cur] + (w * 32 + lm) * 40 + lq * 8);
    af[1] = *(const bf16x8*)(sA[cur] + (w * 32 + 16 + lm) * 40 + lq * 8);
#pragma unroll
    for (int s = 0; s < 4; ++s)
      bfr[s] = *(const bf16x8*)(sB[cur] + (s * 16 + lm) * 40 + lq * 8);
#pragma unroll
    for (int ms = 0; ms < 2; ++ms)
#pragma unroll
      for (int s = 0; s < 4; ++s)
        acc[ms][s] = MFMA16(af[ms], bfr[s], acc[ms][s]);
    if (kt < 15) {
      int nxt = 1 - cur;
      *(bf16x8*)(sA[nxt] + sm * 40 + skc) = a0;
      *(bf16x8*)(sA[nxt] + (sm + 64) * 40 + skc) = a1;
      *(bf16x8*)(sB[nxt] + sm * 40 + skc) = b0;
    }
    __syncthreads();
  }

#pragma unroll
  for (int ms = 0; ms < 2; ++ms) {
    int gmBase = m0 + w * 32 + ms * 16 + lq * 4;
#pragma unroll
    for (int s = 0; s < 4; ++s) {
      int gc = n0 + s * 16 + lm;
      int b = gmBase >> 11, n = gmBase & 2047;
      if (isQ) {
#pragma unroll
        for (int r = 0; r < 4; ++r)
          out_q[(((long)(b << 3) + (gc >> 6)) * 2048 + n + r) * 64 + (gc & 63)] =
              f2bf(acc[ms][s][r] * QSCALE);
      } else if (gc < 512) {
#pragma unroll
        for (int r = 0; r < 4; ++r)
          out_k[(((long)(b << 3) + (gc >> 6)) * 2048 + n + r) * 64 + (gc & 63)] =
              f2bf(acc[ms][s][r]);
      } else {
        int c = gc - 512, h = c >> 6, d = c & 63;
        u16x4 vv;
#pragma unroll
        for (int r = 0; r < 4; ++r) vv[r] = f2bf(acc[ms][s][r]);
        *(u16x4*)(out_vt + (((long)(b << 3) + h) * 64 + d) * 2048 + n) = vv;
      }
    }
  }
}

// ---------------------------------------------------------------------------
// Attention: 512 blocks x 256 thr, wave (g=q-group, kh=key-half).
// K/V staged via global_load_lds DMA into XOR-swizzled unpadded LDS
// (single buffer, 32 KB). Zero staging VGPRs/VALU. Two barriers per j-tile;
// drains overlap the co-resident block's compute.
// ---------------------------------------------------------------------------
__global__ __launch_bounds__(256, 4) void attn(
    const u16* __restrict__ Q, const u16* __restrict__ K,
    const u16* __restrict__ Vt, u16* __restrict__ O) {
  int id = blockIdx.x;
  int bh = id & 15, qt = id >> 4;
  int b = bh >> 3, h = bh & 7;
  const u16* Kh = K + (long)bh * 2048 * 64;
  const u16* Vh = Vt + (long)bh * 64 * 2048;
  int t = threadIdx.x, w = t >> 6, lane = t & 63, ln = lane & 31, hi = lane >> 5;
  int g = w & 1, kh = w >> 1;

  __shared__ u16 smem[2][2][4096];  // [K/V][kh][64 rows x 64 elems, swizzled]
  u16* sKh = smem[0][kh];
  u16* sVh = smem[1][kh];

  bf16x8 qf[4];
  {
    const u16* qp = Q + (long)bh * 2048 * 64 + (long)(qt * 64 + g * 32 + ln) * 64 + hi * 8;
#pragma unroll
    for (int dc = 0; dc < 4; ++dc) qf[dc] = *(const bf16x8*)(qp + dc * 16);
  }

  f32x16 accO[2];
#pragma unroll
  for (int dt = 0; dt < 2; ++dt)
#pragma unroll
    for (int i = 0; i < 16; ++i) accO[dt][i] = 0.f;
  float dacc = 0.f;

  // DMA source addressing (per lane): row-phase and swizzled chunk
  int lrow = lane >> 3;                 // 0..7
  int swz = ((lane & 7) ^ lrow) * 8;    // element offset of 16B chunk in row
  const u16* gKl = Kh + (long)(kh * 1024 + g * 32 + lrow) * 64 + swz;
  const u16* gVl = Vh + (long)(g * 32 + lrow) * 2048 + kh * 1024 + swz;

  auto stage = [&](int jt) {
    const u16* gk = gKl + (long)jt * 4096;
    const u16* gv = gVl + jt * 64;
#pragma unroll
    for (int i = 0; i < 4; ++i) {
      GLD16(gk + i * 512, sKh + (g * 32 + i * 8) * 64);
      GLD16(gv + (long)i * 16384, sVh + (g * 32 + i * 8) * 64);
    }
  };

  stage(0);
  __syncthreads();

  int swl = ln & 7;
  for (int jt = 0; jt < 16; ++jt) {
#pragma unroll
    for (int kt2 = 0; kt2 < 2; ++kt2) {
      int rowK = (kt2 * 32 + ln) * 64;
      f32x16 st1, st2;
#pragma unroll
      for (int i = 0; i < 16; ++i) { st1[i] = 0.f; st2[i] = 0.f; }
      bf16x8 kf0 = *(const bf16x8*)(sKh + rowK + ((0 * 2 + hi) ^ swl) * 8);
      bf16x8 kf1 = *(const bf16x8*)(sKh + rowK + ((1 * 2 + hi) ^ swl) * 8);
      bf16x8 kf2 = *(const bf16x8*)(sKh + rowK + ((2 * 2 + hi) ^ swl) * 8);
      bf16x8 kf3 = *(const bf16x8*)(sKh + rowK + ((3 * 2 + hi) ^ swl) * 8);
      st1 = MFMA3216(kf0, qf[0], st1);
      st2 = MFMA3216(kf1, qf[1], st2);
      st1 = MFMA3216(kf2, qf[2], st1);
      st2 = MFMA3216(kf3, qf[3], st2);
      float p[16];
#pragma unroll
      for (int i = 0; i < 16; ++i) {
        float e = EXPFN(st1[i] + st2[i]);
        p[i] = e;
        dacc += e;
      }
#if HAVE_PV8
#pragma unroll
      for (int c = 0; c < 4; ++c) {
        union { int2 i2; bf16x4 v; } u;
        u.i2.x = pkbf(p[c * 4 + 0], p[c * 4 + 1]);
        u.i2.y = pkbf(p[c * 4 + 2], p[c * 4 + 3]);
#pragma unroll
        for (int dt = 0; dt < 2; ++dt) {
          bf16x4 vf = *(const bf16x4*)(sVh + (dt * 32 + ln) * 64 +
                                       (((kt2 * 4 + c) ^ swl) * 8) + hi * 4);
          accO[dt] = PVMFMA(vf, u.v, accO[dt]);
        }
      }
#else
#pragma unroll
      for (int c2 = 0; c2 < 2; ++c2) {
        int o0x = pkbf(p[c2 * 8 + 0], p[c2 * 8 + 1]);
        int o0y = pkbf(p[c2 * 8 + 2], p[c2 * 8 + 3]);
        int o1x = pkbf(p[c2 * 8 + 4], p[c2 * 8 + 5]);
        int o1y = pkbf(p[c2 * 8 + 6], p[c2 * 8 + 7]);
        int s0x = __shfl_xor(o0x, 32), s0y = __shfl_xor(o0y, 32);
        int s1x = __shfl_xor(o1x, 32), s1y = __shfl_xor(o1y, 32);
        union { int4 i4; bf16x8 v; } u;
        if (hi) { u.i4.x = s1x; u.i4.y = s1y; u.i4.z = o1x; u.i4.w = o1y; }
        else    { u.i4.x = o0x; u.i4.y = o0y; u.i4.z = s0x; u.i4.w = s0y; }
#pragma unroll
        for (int dt = 0; dt < 2; ++dt) {
          bf16x8 vf = *(const bf16x8*)(sVh + (dt * 32 + ln) * 64 +
                                       (((kt2 * 4 + c2 * 2 + hi) ^ swl) * 8));
          accO[dt] = MFMA3216(vf, u.v, accO[dt]);
        }
      }
#endif
    }
    __syncthreads();          // all consumers done with this tile
    if (jt < 15) {
      stage(jt + 1);          // DMA next tile into (single) buffer
      __syncthreads();        // barrier drains each wave's vmcnt -> DMA done
    }
  }

  // combine key-halves via LDS scratch (aliases smem; loop ended on a barrier)
  float* cb = (float*)&smem[0][0][0];
  float* base = cb + g * 2112;
  if (kh == 1) {
#pragma unroll
    for (int dt = 0; dt < 2; ++dt)
#pragma unroll
      for (int i = 0; i < 16; ++i)
        base[(dt * 16 + i) * 64 + hi * 32 + ln] = accO[dt][i];
    base[2048 + hi * 32 + ln] = dacc;
  }
  __syncthreads();
  if (kh == 0) {
#pragma unroll
    for (int dt = 0; dt < 2; ++dt)
#pragma unroll
      for (int i = 0; i < 16; ++i)
        accO[dt][i] += base[(dt * 16 + i) * 64 + hi * 32 + ln];
    dacc += base[2048 + hi * 32 + ln];
    dacc += __shfl_xor(dacc, 32);
    float inv = 1.f / dacc;

    u16* Ob = O + ((long)b * 2048 + qt * 64 + g * 32 + ln) * 512 + h * 64;
#pragma unroll
    for (int dt = 0; dt < 2; ++dt)
#pragma unroll
      for (int gq = 0; gq < 4; ++gq) {
        u16x4 o;
#pragma unroll
        for (int rr = 0; rr < 4; ++rr) o[rr] = f2bf(accO[dt][gq * 4 + rr] * inv);
        *(u16x4*)(Ob + dt * 32 + gq * 8 + hi * 4) = o;
      }
  }
}

// ---------------------------------------------------------------------------
// out GEMM: 64x32 tiles, 1024 blocks x 128 thr, dbuf + register prefetch.
// ---------------------------------------------------------------------------
__global__ __launch_bounds__(128) void out_gemm(
    const u16* __restrict__ A, const u16* __restrict__ BT,
    float* __restrict__ out_f, const float* __restrict__ bias) {
  __shared__ u16 sA[2][64 * 40];
  __shared__ u16 sB[2][32 * 40];
  int t = threadIdx.x, bx = blockIdx.x;
  int m0 = (bx & 63) * 64, n0 = (bx >> 6) * 32;
  int w = t >> 6, l = t & 63, lm = l & 15, lq = l >> 4;

  f32x4 zero = {0.f, 0.f, 0.f, 0.f};
  f32x4 acc[2][2];
#pragma unroll
  for (int i = 0; i < 2; ++i)
#pragma unroll
    for (int j = 0; j < 2; ++j) acc[i][j] = zero;

  int ar = t >> 1, akc = (t & 1) * 16;
  int br = t >> 2, bkc = (t & 3) * 8;
  const u16* gA = A + (long)(m0 + ar) * 512 + akc;
  const u16* gB = BT + (long)(n0 + br) * 512 + bkc;

  bf16x8 a0 = *(const bf16x8*)(gA);
  bf16x8 a1 = *(const bf16x8*)(gA + 8);
  bf16x8 b0 = *(const bf16x8*)(gB);
  *(bf16x8*)(sA[0] + ar * 40 + akc) = a0;
  *(bf16x8*)(sA[0] + ar * 40 + akc + 8) = a1;
  *(bf16x8*)(sB[0] + br * 40 + bkc) = b0;
  __syncthreads();

  for (int kt = 0; kt < 16; ++kt) {
    int cur = kt & 1;
    if (kt < 15) {
      a0 = *(const bf16x8*)(gA + (kt + 1) * 32);
      a1 = *(const bf16x8*)(gA + (kt + 1) * 32 + 8);
      b0 = *(const bf16x8*)(gB + (kt + 1) * 32);
    }
    bf16x8 af[2], bfr[2];
    af[0] = *(const bf16x8*)(sA[cur] + (w * 32 + lm) * 40 + lq * 8);
    af[1] = *(const bf16x8*)(sA[cur] + (w * 32 + 16 + lm) * 40 + lq * 8);
    bfr[0] = *(const bf16x8*)(sB[cur] + (lm)*40 + lq * 8);
    bfr[1] = *(const bf16x8*)(sB[cur] + (16 + lm) * 40 + lq * 8);
#pragma unroll
    for (int ms = 0; ms < 2; ++ms)
#pragma unroll
      for (int s = 0; s < 2; ++s)
        acc[ms][s] = MFMA16(af[ms], bfr[s], acc[ms][s]);
    if (kt < 15) {
      int nxt = 1 - cur;
      *(bf16x8*)(sA[nxt] + ar * 40 + akc) = a0;
      *(bf16x8*)(sA[nxt] + ar * 40 + akc + 8) = a1;
      *(bf16x8*)(sB[nxt] + br * 40 + bkc) = b0;
    }
    __syncthreads();
  }

#pragma unroll
  for (int ms = 0; ms < 2; ++ms) {
    int gmBase = m0 + w * 32 + ms * 16 + lq * 4;
#pragma unroll
    for (int s = 0; s < 2; ++s) {
      int gc = n0 + s * 16 + lm;
      float bv = bias[gc];
#pragma unroll
      for (int r = 0; r < 4; ++r)
        out_f[(long)(gmBase + r) * 512 + gc] = acc[ms][s][r] + bv;
    }
  }
}

// ---------------------------------------------------------------------------
extern "C" void kernel_launch(void* const* d_in, const int* in_sizes, int n_in,
                              void* d_out, int out_size, void* d_ws, size_t ws_size,
                              hipStream_t stream) {
  const float* x1 = (const float*)d_in[0];
  const float* x2 = (const float*)d_in[1];
  const float* Wqk = (const float*)d_in[2];
  const float* Wv = (const float*)d_in[3];
  const float* Wout = (const float*)d_in[4];
  const float* bout = (const float*)d_in[5];
  float* out = (float*)d_out;

  u16* ws = (u16*)d_ws;
  const long SZ = 2097152;  // 2*8*2048*64
  u16* Qw = ws;
  u16* Kw = ws + SZ;
  u16* Vtw = ws + 2 * SZ;
  u16* Ow = ws + 3 * SZ;
  u16* WqkT = ws + 4 * SZ;
  u16* WvT = WqkT + 524288;
  u16* WoutT = WvT + 262144;

  wprep<<<1024, 256, 0, stream>>>(Wqk, Wv, Wout, WqkT, WvT, WoutT);
  qkv_gemm<<<768, 256, 0, stream>>>(x1, x2, WqkT, WvT, Qw, Kw, Vtw);
  attn<<<512, 256, 0, stream>>>(Qw, Kw, Vtw, Ow);
  out_gemm<<<1024, 128, 0, stream>>>(Ow, WoutT, out, bout);
}